// Round 16
// baseline (403.843 us; speedup 1.0000x reference)
//
#include <hip/hip_runtime.h>

// SAGEEncoder v16: v15 (frag-major weights) + sage at 8 blocks/CU:
// aggU[64][68]dw (max|mean only, 17.4KB), x A-frags direct from bf16 mirror.
// Safe now: frag-major addressing needs only ~40 VGPRs (v10's spill was
// row-major address pressure).

#define INFF 3.402823466e38f

typedef __attribute__((ext_vector_type(8))) short bf16x8;
typedef __attribute__((ext_vector_type(4))) float f32x4;

__device__ __forceinline__ unsigned short f2bf(float f) {
  unsigned u = __float_as_uint(f);
  u = (u + 0x7FFFu + ((u >> 16) & 1u)) >> 16;
  return (unsigned short)u;
}
__device__ __forceinline__ unsigned pack2(float a, float b) {
  return (unsigned)f2bf(a) | ((unsigned)f2bf(b) << 16);
}
__device__ __forceinline__ float bf_lo(unsigned u) { return __uint_as_float(u << 16); }
__device__ __forceinline__ float bf_hi(unsigned u) { return __uint_as_float(u & 0xFFFF0000u); }

// int64 iff the first 32 odd u32 slots are all zero
__device__ __forceinline__ int detect64(const unsigned* __restrict__ e) {
  int is64 = 1;
#pragma unroll
  for (int i = 0; i < 32; ++i) is64 &= (e[2 * i + 1] == 0u) ? 1 : 0;
  return is64;
}

__device__ __forceinline__ int edge_val(const void* e, int is64, long long idx) {
  if (is64) return (int)((const long long*)e)[idx];
  return ((const int*)e)[idx];
}

// ---- radix-bucket CSR build (buckets of 256 nodes by dst>>8) ----
__global__ void bucket_count(const void* __restrict__ edges, int* __restrict__ bcnt,
                             int nE, int nbk) {
  __shared__ int h[512];
  int t = threadIdx.x;
  for (int i = t; i < nbk; i += 256) h[i] = 0;
  __syncthreads();
  int is64 = detect64((const unsigned*)edges);
  long long E = nE;
  for (int i = blockIdx.x * 256 + t; i < nE; i += gridDim.x * 256) {
    int dst = edge_val(edges, is64, E + i);
    atomicAdd(&h[dst >> 8], 1);
  }
  __syncthreads();
  for (int i = t; i < nbk; i += 256) {
    int v = h[i];
    if (v) atomicAdd(&bcnt[i], v);
  }
}

// single block: exclusive scan of bcnt[nbk] (nbk <= 512)
__global__ void bucket_scan(const int* __restrict__ bcnt, int* __restrict__ bstart,
                            int* __restrict__ bcursor, int* __restrict__ row_start,
                            int nbk, int nE, int nN) {
  __shared__ int s[512];
  int t = threadIdx.x;
  int v = (t < nbk) ? bcnt[t] : 0;
  s[t] = v;
  __syncthreads();
  for (int off = 1; off < 512; off <<= 1) {
    int u = (t >= off) ? s[t - off] : 0;
    __syncthreads();
    s[t] += u;
    __syncthreads();
  }
  if (t < nbk) {
    int ex = s[t] - v;
    bstart[t] = ex;
    bcursor[t] = ex;
  }
  if (t == 0) {
    bstart[nbk] = nE;
    row_start[nN] = nE;
  }
}

// block-aggregated scatter: LDS histogram -> 1 cursor atomic per bucket per
// block -> LDS-cursor scatter into dense reserved ranges.
#define SCH 16  // edges per thread per chunk (chunk = 4096)
__global__ __launch_bounds__(256) void bucket_scatter(
    const void* __restrict__ edges, int* __restrict__ bcursor,
    unsigned* __restrict__ bbuf, int nE, int nbk) {
  __shared__ int cnt[512];
  __shared__ int basep[512];
  int t = threadIdx.x;
  int is64 = detect64((const unsigned*)edges);
  long long E = nE;
  const int chunk = 256 * SCH;
  for (int c0 = blockIdx.x * chunk; c0 < nE; c0 += gridDim.x * chunk) {
    for (int i = t; i < nbk; i += 256) cnt[i] = 0;
    __syncthreads();
    unsigned pk[SCH];
    short bk[SCH];
#pragma unroll
    for (int u = 0; u < SCH; ++u) {
      int i = c0 + u * 256 + t;  // coalesced
      if (i < nE) {
        int src = edge_val(edges, is64, i);
        int dst = edge_val(edges, is64, E + i);
        pk[u] = ((unsigned)(dst & 255) << 24) | (unsigned)src;
        bk[u] = (short)(dst >> 8);
        atomicAdd(&cnt[bk[u]], 1);
      } else {
        bk[u] = -1;
      }
    }
    __syncthreads();
    for (int i = t; i < nbk; i += 256) {
      int c = cnt[i];
      basep[i] = c ? atomicAdd(&bcursor[i], c) : 0;
    }
    __syncthreads();
    for (int i = t; i < nbk; i += 256) cnt[i] = 0;
    __syncthreads();
#pragma unroll
    for (int u = 0; u < SCH; ++u) {
      if (bk[u] >= 0) {
        int local = atomicAdd(&cnt[bk[u]], 1);
        bbuf[basep[bk[u]] + local] = pk[u];
      }
    }
    __syncthreads();
  }
}

// one block per bucket: LDS histogram+scan -> row_start; local scatter -> csr_src
__global__ __launch_bounds__(256) void bucket_to_csr(
    const unsigned* __restrict__ bbuf, const int* __restrict__ bstart,
    int* __restrict__ row_start, int* __restrict__ csr_src, int nN) {
  __shared__ int cnt[256], cur[256], sc[256];
  int b = blockIdx.x, t = threadIdx.x;
  int bs = bstart[b], be = bstart[b + 1];
  cnt[t] = 0;
  __syncthreads();
  for (int i = bs + t; i < be; i += 256) atomicAdd(&cnt[bbuf[i] >> 24], 1);
  __syncthreads();
  int v = cnt[t];
  sc[t] = v;
  __syncthreads();
  for (int off = 1; off < 256; off <<= 1) {
    int u = (t >= off) ? sc[t - off] : 0;
    __syncthreads();
    sc[t] += u;
    __syncthreads();
  }
  int ex = sc[t] - v;
  int node = b * 256 + t;
  if (node < nN) row_start[node] = bs + ex;
  cur[t] = ex;
  __syncthreads();
  for (int i = bs + t; i < be; i += 256) {
    unsigned e = bbuf[i];
    int p = atomicAdd(&cur[e >> 24], 1);
    csr_src[bs + p] = (int)(e & 0xFFFFFFu);
  }
}

// ---- fragment-major bf16 weight conversion + x->bf16 mirror ----
__global__ void prep_all(const float* __restrict__ wl, const float* __restrict__ wr,
                         const float* __restrict__ aw, const float* __restrict__ w1,
                         const float* __restrict__ w2, const float* __restrict__ x,
                         unsigned short* __restrict__ wcatf, unsigned short* __restrict__ awbf,
                         unsigned short* __restrict__ w1f, unsigned short* __restrict__ w2f,
                         unsigned short* __restrict__ xb, int nl, int n4) {
  int i = blockIdx.x * 256 + threadIdx.x;
  int tot = nl * 12288;
  int wtot = tot + 4096 + 16384 + 16384;
  if (i < tot) {
    int l = i / 12288, r = i % 12288;
    int e = r & 7, lane = (r >> 3) & 63, idx = r >> 9;  // idx = ft*6+ks (0..23)
    int ft = idx / 6, ks = idx % 6;
    int f = ft * 16 + (lane & 15);
    int k = ks * 32 + (lane >> 4) * 8 + e;
    float v = (k < 128) ? wl[l * 8192 + f * 128 + k] : wr[l * 4096 + f * 64 + (k - 128)];
    wcatf[i] = f2bf(v);
  } else if (i < wtot) {
    int j = i - tot;
    if (j < 4096) {  // awbf: idx = ft*2+k2 (0..7)
      int e = j & 7, lane = (j >> 3) & 63, idx = j >> 9;
      int f = (idx >> 1) * 16 + (lane & 15);
      int k = (idx & 1) * 32 + (lane >> 4) * 8 + e;
      awbf[j] = f2bf(aw[f * 64 + k]);
    } else if (j < 4096 + 16384) {  // w1f: idx = ptg*2+ks (0..31)
      int q = j - 4096;
      int e = q & 7, lane = (q >> 3) & 63, idx = q >> 9;
      int p = (idx >> 1) * 16 + (lane & 15);
      int k = (idx & 1) * 32 + (lane >> 4) * 8 + e;
      w1f[q] = f2bf(w1[p * 64 + k]);
    } else {  // w2f: idx = ft*8+ks (0..31)
      int q = j - 20480;
      int e = q & 7, lane = (q >> 3) & 63, idx = q >> 9;
      int f = (idx >> 3) * 16 + (lane & 15);
      int k = (idx & 7) * 32 + (lane >> 4) * 8 + e;
      w2f[q] = f2bf(w2[f * 256 + k]);
    }
  } else {
    int q = i - wtot;
    if (q < n4) {
      float4 v = ((const float4*)x)[q];
      ushort4 o;
      o.x = f2bf(v.x); o.y = f2bf(v.y); o.z = f2bf(v.z); o.w = f2bf(v.w);
      ((ushort4*)xb)[q] = o;
    }
  }
}

// ---- fused SAGE layer: shfl gather + MFMA GEMM + in-wave LN ----
// Block 256 (4 waves), 64 nodes. aggU[64][68]dw (17 quads odd -> clean b128);
// x A-frags direct from bf16 mirror. 8 blocks/CU.
template <bool FIRST>
__global__ __launch_bounds__(256, 8) void sage_layer(
    const float* __restrict__ inf, const unsigned short* __restrict__ inb,
    float* __restrict__ outf, unsigned short* __restrict__ outb,
    const int* __restrict__ row_start, const int* __restrict__ csr_src,
    const unsigned short* __restrict__ wcatf,  // frag-major [24][64][8]
    const unsigned short* __restrict__ awbf,   // frag-major [8][64][8]
    const float* __restrict__ bl, const float* __restrict__ ab,
    const float* __restrict__ lng, const float* __restrict__ lnb,
    int nN, int wf32) {
  __shared__ unsigned aggU[64 * 68];

  int t = threadIdx.x;
  int wv = __builtin_amdgcn_readfirstlane(t >> 6);
  int lane = t & 63;
  int g_lane = lane >> 4;
  int fq4 = (lane & 15) * 4;
  int foff = fq4 * 2;
  int base = blockIdx.x * 64;
  int wn0 = base + wv * 16;

  int rlv = row_start[min(wn0 + min(lane, 16), nN)];
  int rs[17];
#pragma unroll
  for (int i = 0; i <= 16; ++i) rs[i] = __builtin_amdgcn_readlane(rlv, i);

  int offL[4], dgL[4], dgmL[4];
#pragma unroll
  for (int G = 0; G < 4; ++G) {
    int a_ = __shfl(rlv, 4 * G + g_lane);
    int b_ = __shfl(rlv, 4 * G + g_lane + 1);
    offL[G] = a_ - rs[4 * G];
    dgL[G] = b_ - a_;
    dgmL[G] = max(dgL[G] - 1, 0);
  }

  int ivA[4], ivB[4];
#pragma unroll
  for (int G = 0; G < 4; ++G) {
    int Eg = rs[4 * G];
    int lenm1 = max(rs[4 * G + 4] - Eg - 1, 0);
    ivA[G] = min((unsigned)csr_src[Eg + min(lane, lenm1)], (unsigned)(nN - 1));
    ivB[G] = min((unsigned)csr_src[Eg + min(lane + 64, lenm1)], (unsigned)(nN - 1));
  }

  // gather (bf16 mirror): 4 nodes lockstep, 16-edge batches
#pragma unroll
  for (int G = 0; G < 4; ++G) {
    int Eg = rs[4 * G];
    int len = rs[4 * G + 4] - Eg;
    int d0 = rs[4 * G + 1] - rs[4 * G + 0], d1 = rs[4 * G + 2] - rs[4 * G + 1];
    int d2 = rs[4 * G + 3] - rs[4 * G + 2], d3 = rs[4 * G + 4] - rs[4 * G + 3];
    int mm = max(max(d0, d1), max(d2, d3));
    int offl = offL[G], dgl = dgL[G], dgml = dgmL[G];
    float4 mx = make_float4(-INFF, -INFF, -INFF, -INFF);
    float4 sm = make_float4(0.f, 0.f, 0.f, 0.f);

    if (len <= 64) {
      for (int tt = 0; tt < mm; tt += 16) {
        uint2 v[16];
#pragma unroll
        for (int u = 0; u < 16; ++u) {
          int p = offl + min(tt + u, dgml);
          int si = __shfl(ivA[G], p);
          v[u] = *(const uint2*)((const char*)inb + ((si << 7) + foff));
        }
#pragma unroll
        for (int u = 0; u < 16; ++u) {
          float f0 = bf_lo(v[u].x), f1 = bf_hi(v[u].x);
          float f2 = bf_lo(v[u].y), f3 = bf_hi(v[u].y);
          float m = (tt + u < dgl) ? 1.f : 0.f;
          mx.x = fmaxf(mx.x, f0); mx.y = fmaxf(mx.y, f1);
          mx.z = fmaxf(mx.z, f2); mx.w = fmaxf(mx.w, f3);
          sm.x = fmaf(f0, m, sm.x); sm.y = fmaf(f1, m, sm.y);
          sm.z = fmaf(f2, m, sm.z); sm.w = fmaf(f3, m, sm.w);
        }
      }
    } else if (len <= 128) {
      for (int tt = 0; tt < mm; tt += 8) {
        uint2 v[8];
#pragma unroll
        for (int u = 0; u < 8; ++u) {
          int p = offl + min(tt + u, dgml);
          int a = __shfl(ivA[G], p & 63);
          int b = __shfl(ivB[G], p & 63);
          int si = (p < 64) ? a : b;
          v[u] = *(const uint2*)((const char*)inb + ((si << 7) + foff));
        }
#pragma unroll
        for (int u = 0; u < 8; ++u) {
          float f0 = bf_lo(v[u].x), f1 = bf_hi(v[u].x);
          float f2 = bf_lo(v[u].y), f3 = bf_hi(v[u].y);
          float m = (tt + u < dgl) ? 1.f : 0.f;
          mx.x = fmaxf(mx.x, f0); mx.y = fmaxf(mx.y, f1);
          mx.z = fmaxf(mx.z, f2); mx.w = fmaxf(mx.w, f3);
          sm.x = fmaf(f0, m, sm.x); sm.y = fmaf(f1, m, sm.y);
          sm.z = fmaf(f2, m, sm.z); sm.w = fmaf(f3, m, sm.w);
        }
      }
    } else {
      for (int tt = 0; tt < mm; tt += 4) {
        uint2 v[4];
#pragma unroll
        for (int u = 0; u < 4; ++u) {
          int p = offl + min(tt + u, dgml);
          unsigned si = min((unsigned)csr_src[Eg + p], (unsigned)(nN - 1));
          v[u] = *(const uint2*)((const char*)inb + (((int)si << 7) + foff));
        }
#pragma unroll
        for (int u = 0; u < 4; ++u) {
          float f0 = bf_lo(v[u].x), f1 = bf_hi(v[u].x);
          float f2 = bf_lo(v[u].y), f3 = bf_hi(v[u].y);
          float m = (tt + u < dgl) ? 1.f : 0.f;
          mx.x = fmaxf(mx.x, f0); mx.y = fmaxf(mx.y, f1);
          mx.z = fmaxf(mx.z, f2); mx.w = fmaxf(mx.w, f3);
          sm.x = fmaf(f0, m, sm.x); sm.y = fmaf(f1, m, sm.y);
          sm.z = fmaf(f2, m, sm.z); sm.w = fmaf(f3, m, sm.w);
        }
      }
    }

    int rowU = (wv * 16 + G * 4 + g_lane) * 68;
    float ok = (dgl > 0) ? 1.f : 0.f;
    float r = 1.f / (float)max(dgl, 1);
    aggU[rowU + (fq4 >> 1)] = pack2(ok * mx.x, ok * mx.y);
    aggU[rowU + (fq4 >> 1) + 1] = pack2(ok * mx.z, ok * mx.w);
    aggU[rowU + 32 + (fq4 >> 1)] = pack2(sm.x * r, sm.y * r);
    aggU[rowU + 32 + (fq4 >> 1) + 1] = pack2(sm.z * r, sm.w * r);
  }
  __syncthreads();

  // ---- MFMA GEMM: wave = node-tile wv; acc[ft] covers f-tiles 0..3 ----
  int ml = lane & 15, gq = lane >> 4;
  bf16x8 afr[6];
  const char* arow = (const char*)aggU + (size_t)(wv * 16 + ml) * 272;
  afr[0] = *(const bf16x8*)(arow + gq * 16);
  afr[1] = *(const bf16x8*)(arow + 64 + gq * 16);
  afr[2] = *(const bf16x8*)(arow + 128 + gq * 16);
  afr[3] = *(const bf16x8*)(arow + 192 + gq * 16);
  unsigned anode = min((unsigned)(base + wv * 16 + ml), (unsigned)(nN - 1));
  const char* xrow = (const char*)inb + (size_t)anode * 128;
  afr[4] = *(const bf16x8*)(xrow + gq * 16);
  afr[5] = *(const bf16x8*)(xrow + 64 + gq * 16);

  f32x4 acc[4], accr[4];
#pragma unroll
  for (int ft = 0; ft < 4; ++ft) {
    acc[ft] = (f32x4){0.f, 0.f, 0.f, 0.f};
#pragma unroll
    for (int ks = 0; ks < 6; ++ks) {
      bf16x8 b = *(const bf16x8*)(wcatf + ((ft * 6 + ks) << 9) + (lane << 3));
      acc[ft] = __builtin_amdgcn_mfma_f32_16x16x32_bf16(afr[ks], b, acc[ft], 0, 0, 0);
    }
    if (FIRST) {
      accr[ft] = (f32x4){0.f, 0.f, 0.f, 0.f};
#pragma unroll
      for (int k2 = 0; k2 < 2; ++k2) {
        bf16x8 b = *(const bf16x8*)(awbf + ((ft * 2 + k2) << 9) + (lane << 3));
        accr[ft] = __builtin_amdgcn_mfma_f32_16x16x32_bf16(afr[4 + k2], b, accr[ft], 0, 0, 0);
      }
    }
  }

  // ---- epilogue: bias, in-wave LN, residual, SiLU, store ----
  float blv[4], gv[4], bvv[4], abv[4];
#pragma unroll
  for (int ft = 0; ft < 4; ++ft) {
    blv[ft] = bl[ft * 16 + ml];
    gv[ft] = lng[ft * 16 + ml];
    bvv[ft] = lnb[ft * 16 + ml];
    if (FIRST) abv[ft] = ab[ft * 16 + ml];
  }
  float v[4][4];
  float s1[4] = {0.f, 0.f, 0.f, 0.f}, s2[4] = {0.f, 0.f, 0.f, 0.f};
#pragma unroll
  for (int ft = 0; ft < 4; ++ft)
#pragma unroll
    for (int reg = 0; reg < 4; ++reg) {
      float a = acc[ft][reg] + blv[ft];
      v[ft][reg] = a;
      s1[reg] += a;
      s2[reg] = fmaf(a, a, s2[reg]);
    }
#pragma unroll
  for (int m = 1; m < 16; m <<= 1)
#pragma unroll
    for (int reg = 0; reg < 4; ++reg) {
      s1[reg] += __shfl_xor(s1[reg], m);
      s2[reg] += __shfl_xor(s2[reg], m);
    }

#pragma unroll
  for (int reg = 0; reg < 4; ++reg) {
    float mean = s1[reg] * 0.015625f;
    float var = s2[reg] * 0.015625f - mean * mean;
    float rs_ = rsqrtf(var + 1e-5f);
    int nj = base + wv * 16 + gq * 4 + reg;
    unsigned njc = min((unsigned)nj, (unsigned)(nN - 1));
    bool ok = nj < nN;
#pragma unroll
    for (int ft = 0; ft < 4; ++ft) {
      float res = FIRST ? (accr[ft][reg] + abv[ft])
                        : inf[(size_t)njc * 64 + ft * 16 + ml];
      float y = (v[ft][reg] - mean) * rs_ * gv[ft] + bvv[ft] + res;
      float h = y / (1.f + __expf(-y));
      if (ok) {
        if (wf32) outf[(size_t)nj * 64 + ft * 16 + ml] = h;
        outb[(size_t)nj * 64 + ft * 16 + ml] = f2bf(h);
      }
    }
  }
}

// ---- MLP head (v15): frag-major weights ----
__global__ __launch_bounds__(512) void mlp_head(
    const unsigned short* __restrict__ inb, float* __restrict__ out,
    const unsigned short* __restrict__ w1f, const float* __restrict__ b1,
    const float* __restrict__ lng, const float* __restrict__ lnb,
    const unsigned short* __restrict__ w2f, const float* __restrict__ b2, int nN) {
  __shared__ unsigned short up[64 * 264];
  __shared__ float ln1[128], ln2[128];

  int t = threadIdx.x;
  int wv = __builtin_amdgcn_readfirstlane(t >> 6);
  int lane = t & 63;
  int ml = lane & 15, gq = lane >> 4;
  int base = blockIdx.x * 64;
  int nt = wv & 3, ph = wv >> 2;

  int nodeA = min(base + nt * 16 + ml, nN - 1);
  const char* arow = (const char*)inb + (size_t)nodeA * 128;
  bf16x8 a0 = *(const bf16x8*)(arow + gq * 16);
  bf16x8 a1 = *(const bf16x8*)(arow + 64 + gq * 16);

  f32x4 acc[8];
#pragma unroll
  for (int pt = 0; pt < 8; ++pt) {
    int ptg = ph * 8 + pt;
    bf16x8 b0 = *(const bf16x8*)(w1f + ((ptg * 2 + 0) << 9) + (lane << 3));
    bf16x8 b1fr = *(const bf16x8*)(w1f + ((ptg * 2 + 1) << 9) + (lane << 3));
    f32x4 c = (f32x4){0.f, 0.f, 0.f, 0.f};
    c = __builtin_amdgcn_mfma_f32_16x16x32_bf16(a0, b0, c, 0, 0, 0);
    c = __builtin_amdgcn_mfma_f32_16x16x32_bf16(a1, b1fr, c, 0, 0, 0);
    acc[pt] = c;
  }

  float s1[4] = {0.f, 0.f, 0.f, 0.f}, s2[4] = {0.f, 0.f, 0.f, 0.f};
#pragma unroll
  for (int pt = 0; pt < 8; ++pt) {
    float bb = b1[ph * 128 + pt * 16 + ml];
#pragma unroll
    for (int reg = 0; reg < 4; ++reg) {
      float u = acc[pt][reg] + bb;
      u = u / (1.f + __expf(-u));
      acc[pt][reg] = u;
      s1[reg] += u;
      s2[reg] = fmaf(u, u, s2[reg]);
    }
  }
#pragma unroll
  for (int m = 1; m < 16; m <<= 1)
#pragma unroll
    for (int reg = 0; reg < 4; ++reg) {
      s1[reg] += __shfl_xor(s1[reg], m);
      s2[reg] += __shfl_xor(s2[reg], m);
    }
  if (ml == 0) {
#pragma unroll
    for (int reg = 0; reg < 4; ++reg) {
      ln1[wv * 16 + gq * 4 + reg] = s1[reg];
      ln2[wv * 16 + gq * 4 + reg] = s2[reg];
    }
  }
  __syncthreads();
  float mean[4], rsv[4];
#pragma unroll
  for (int reg = 0; reg < 4; ++reg) {
    float t1 = s1[reg] + ln1[(wv ^ 4) * 16 + gq * 4 + reg];
    float t2 = s2[reg] + ln2[(wv ^ 4) * 16 + gq * 4 + reg];
    float mn = t1 * 0.00390625f;
    float var = t2 * 0.00390625f - mn * mn;
    mean[reg] = mn;
    rsv[reg] = rsqrtf(var + 1e-5f);
  }
#pragma unroll
  for (int pt = 0; pt < 8; ++pt) {
    int p = ph * 128 + pt * 16 + ml;
    float gg = lng[p], bb = lnb[p];
#pragma unroll
    for (int reg = 0; reg < 4; ++reg) {
      float val = (acc[pt][reg] - mean[reg]) * rsv[reg] * gg + bb;
      up[(nt * 16 + gq * 4 + reg) * 264 + p] = f2bf(val);
    }
  }
  __syncthreads();

  f32x4 o0 = (f32x4){0.f, 0.f, 0.f, 0.f};
  f32x4 o1 = (f32x4){0.f, 0.f, 0.f, 0.f};
  const char* urow = (const char*)up + (size_t)(nt * 16 + ml) * 528;
  int ftA = ph * 2, ftB = ph * 2 + 1;
#pragma unroll
  for (int ks = 0; ks < 8; ++ks) {
    bf16x8 a = *(const bf16x8*)(urow + ks * 64 + gq * 16);
    bf16x8 bA = *(const bf16x8*)(w2f + ((ftA * 8 + ks) << 9) + (lane << 3));
    bf16x8 bB = *(const bf16x8*)(w2f + ((ftB * 8 + ks) << 9) + (lane << 3));
    o0 = __builtin_amdgcn_mfma_f32_16x16x32_bf16(a, bA, o0, 0, 0, 0);
    o1 = __builtin_amdgcn_mfma_f32_16x16x32_bf16(a, bB, o1, 0, 0, 0);
  }
  float b2A = b2[ftA * 16 + ml], b2B = b2[ftB * 16 + ml];
#pragma unroll
  for (int reg = 0; reg < 4; ++reg) {
    int nj = base + nt * 16 + gq * 4 + reg;
    if (nj < nN) {
      out[(size_t)nj * 64 + ftA * 16 + ml] = o0[reg] + b2A;
      out[(size_t)nj * 64 + ftB * 16 + ml] = o1[reg] + b2B;
    }
  }
}

extern "C" void kernel_launch(void* const* d_in, const int* in_sizes, int n_in,
                              void* d_out, int out_size, void* d_ws, size_t ws_size,
                              hipStream_t stream) {
  const float* x = (const float*)d_in[0];
  const void* edges = d_in[1];
  const float* conv_wl = (const float*)d_in[2];
  const float* conv_bl = (const float*)d_in[3];
  const float* conv_wr = (const float*)d_in[4];
  const float* ln_g = (const float*)d_in[5];
  const float* ln_b = (const float*)d_in[6];
  const float* adapter_w = (const float*)d_in[7];
  const float* adapter_b = (const float*)d_in[8];
  const float* mlp_w1 = (const float*)d_in[9];
  const float* mlp_b1 = (const float*)d_in[10];
  const float* mlp_lng = (const float*)d_in[11];
  const float* mlp_lnb = (const float*)d_in[12];
  const float* mlp_w2 = (const float*)d_in[13];
  const float* mlp_b2 = (const float*)d_in[14];

  const int N = in_sizes[0] / 64;
  const int E = in_sizes[1] / 2;
  const int NL = in_sizes[2] / (64 * 128);  // 5

  const int Na = (N + 63) & ~63;
  const int Ea = (E + 63) & ~63;
  const int nbk = (N + 255) / 256;  // buckets of 256 nodes (<=512)

  int* row_start = (int*)d_ws;
  int* csr_src = row_start + (Na + 64);
  int* bcnt = csr_src + (Ea + 256);
  int* bstart = bcnt + (nbk + 8);
  int* bcursor = bstart + (nbk + 8);
  unsigned short* wcatf = (unsigned short*)(bcursor + (nbk + 8));
  unsigned short* awbf = wcatf + (size_t)NL * 12288;
  unsigned short* w1f = awbf + 4096;
  unsigned short* w2f = w1f + 16384;
  unsigned short* b0 = w2f + 16384;
  unsigned short* b1m = b0 + (size_t)Na * 64;
  unsigned* bbuf = (unsigned*)b1m;  // alias: bbuf dead before layer 0 writes b1m
  float* outf = (float*)d_out;

  hipMemsetAsync(bcnt, 0, (size_t)(nbk + 8) * 4, stream);

  bucket_count<<<512, 256, 0, stream>>>(edges, bcnt, E, nbk);
  bucket_scan<<<1, 512, 0, stream>>>(bcnt, bstart, bcursor, row_start, nbk, E, N);
  const int chunk = 256 * SCH;
  const int nsb2 = (E + chunk - 1) / chunk;
  bucket_scatter<<<nsb2, 256, 0, stream>>>(edges, bcursor, bbuf, E, nbk);
  bucket_to_csr<<<nbk, 256, 0, stream>>>(bbuf, bstart, row_start, csr_src, N);

  int prep_tot = NL * 12288 + 4096 + 16384 + 16384;
  int n4 = N * 16;
  int prep_blocks = (prep_tot + n4 + 255) / 256;
  prep_all<<<prep_blocks, 256, 0, stream>>>(conv_wl, conv_wr, adapter_w, mlp_w1, mlp_w2,
                                            x, wcatf, awbf, w1f, w2f, b0, NL, n4);

  const int nb = (N + 63) / 64;
  for (int i = 0; i < NL; ++i) {
    const float* inf = (i == 0) ? x : outf;
    unsigned short* inb = (i & 1) ? b1m : b0;
    unsigned short* outb = (i & 1) ? b0 : b1m;
    const unsigned short* wc = wcatf + (size_t)i * 12288;
    const float* bl = conv_bl + (size_t)i * 64;
    const float* g = ln_g + (size_t)i * 64;
    const float* b = ln_b + (size_t)i * 64;
    int wf32 = (i == NL - 1) ? 0 : 1;
    if (i == 0) {
      sage_layer<true><<<nb, 256, 0, stream>>>(inf, inb, outf, outb, row_start, csr_src,
                                               wc, awbf, bl, adapter_b, g, b, N, wf32);
    } else {
      sage_layer<false><<<nb, 256, 0, stream>>>(inf, inb, outf, outb, row_start, csr_src,
                                                wc, awbf, bl, adapter_b, g, b, N, wf32);
    }
  }
  unsigned short* hb_final = ((NL - 1) & 1) ? b0 : b1m;
  mlp_head<<<nb, 512, 0, stream>>>(hb_final, outf, w1f, mlp_b1, mlp_lng, mlp_lnb,
                                   w2f, mlp_b2, N);
}

// Round 17
// 361.898 us; speedup vs baseline: 1.1159x; 1.1159x over previous
//
#include <hip/hip_runtime.h>

// SAGEEncoder v17: v15 + sage at 7 blocks/CU (aggU[64][68]dw, x A-frags from
// bf16 mirror, VGPR cap 73 so the gather batch stays in registers — the
// (256,8)/64-cap variant spilled, r16).

#define INFF 3.402823466e38f

typedef __attribute__((ext_vector_type(8))) short bf16x8;
typedef __attribute__((ext_vector_type(4))) float f32x4;

__device__ __forceinline__ unsigned short f2bf(float f) {
  unsigned u = __float_as_uint(f);
  u = (u + 0x7FFFu + ((u >> 16) & 1u)) >> 16;
  return (unsigned short)u;
}
__device__ __forceinline__ unsigned pack2(float a, float b) {
  return (unsigned)f2bf(a) | ((unsigned)f2bf(b) << 16);
}
__device__ __forceinline__ float bf_lo(unsigned u) { return __uint_as_float(u << 16); }
__device__ __forceinline__ float bf_hi(unsigned u) { return __uint_as_float(u & 0xFFFF0000u); }

// int64 iff the first 32 odd u32 slots are all zero
__device__ __forceinline__ int detect64(const unsigned* __restrict__ e) {
  int is64 = 1;
#pragma unroll
  for (int i = 0; i < 32; ++i) is64 &= (e[2 * i + 1] == 0u) ? 1 : 0;
  return is64;
}

__device__ __forceinline__ int edge_val(const void* e, int is64, long long idx) {
  if (is64) return (int)((const long long*)e)[idx];
  return ((const int*)e)[idx];
}

// ---- radix-bucket CSR build (buckets of 256 nodes by dst>>8) ----
__global__ void bucket_count(const void* __restrict__ edges, int* __restrict__ bcnt,
                             int nE, int nbk) {
  __shared__ int h[512];
  int t = threadIdx.x;
  for (int i = t; i < nbk; i += 256) h[i] = 0;
  __syncthreads();
  int is64 = detect64((const unsigned*)edges);
  long long E = nE;
  for (int i = blockIdx.x * 256 + t; i < nE; i += gridDim.x * 256) {
    int dst = edge_val(edges, is64, E + i);
    atomicAdd(&h[dst >> 8], 1);
  }
  __syncthreads();
  for (int i = t; i < nbk; i += 256) {
    int v = h[i];
    if (v) atomicAdd(&bcnt[i], v);
  }
}

// single block: exclusive scan of bcnt[nbk] (nbk <= 512)
__global__ void bucket_scan(const int* __restrict__ bcnt, int* __restrict__ bstart,
                            int* __restrict__ bcursor, int* __restrict__ row_start,
                            int nbk, int nE, int nN) {
  __shared__ int s[512];
  int t = threadIdx.x;
  int v = (t < nbk) ? bcnt[t] : 0;
  s[t] = v;
  __syncthreads();
  for (int off = 1; off < 512; off <<= 1) {
    int u = (t >= off) ? s[t - off] : 0;
    __syncthreads();
    s[t] += u;
    __syncthreads();
  }
  if (t < nbk) {
    int ex = s[t] - v;
    bstart[t] = ex;
    bcursor[t] = ex;
  }
  if (t == 0) {
    bstart[nbk] = nE;
    row_start[nN] = nE;
  }
}

// block-aggregated scatter
#define SCH 16
__global__ __launch_bounds__(256) void bucket_scatter(
    const void* __restrict__ edges, int* __restrict__ bcursor,
    unsigned* __restrict__ bbuf, int nE, int nbk) {
  __shared__ int cnt[512];
  __shared__ int basep[512];
  int t = threadIdx.x;
  int is64 = detect64((const unsigned*)edges);
  long long E = nE;
  const int chunk = 256 * SCH;
  for (int c0 = blockIdx.x * chunk; c0 < nE; c0 += gridDim.x * chunk) {
    for (int i = t; i < nbk; i += 256) cnt[i] = 0;
    __syncthreads();
    unsigned pk[SCH];
    short bk[SCH];
#pragma unroll
    for (int u = 0; u < SCH; ++u) {
      int i = c0 + u * 256 + t;
      if (i < nE) {
        int src = edge_val(edges, is64, i);
        int dst = edge_val(edges, is64, E + i);
        pk[u] = ((unsigned)(dst & 255) << 24) | (unsigned)src;
        bk[u] = (short)(dst >> 8);
        atomicAdd(&cnt[bk[u]], 1);
      } else {
        bk[u] = -1;
      }
    }
    __syncthreads();
    for (int i = t; i < nbk; i += 256) {
      int c = cnt[i];
      basep[i] = c ? atomicAdd(&bcursor[i], c) : 0;
    }
    __syncthreads();
    for (int i = t; i < nbk; i += 256) cnt[i] = 0;
    __syncthreads();
#pragma unroll
    for (int u = 0; u < SCH; ++u) {
      if (bk[u] >= 0) {
        int local = atomicAdd(&cnt[bk[u]], 1);
        bbuf[basep[bk[u]] + local] = pk[u];
      }
    }
    __syncthreads();
  }
}

// one block per bucket: LDS histogram+scan -> row_start; local scatter -> csr_src
__global__ __launch_bounds__(256) void bucket_to_csr(
    const unsigned* __restrict__ bbuf, const int* __restrict__ bstart,
    int* __restrict__ row_start, int* __restrict__ csr_src, int nN) {
  __shared__ int cnt[256], cur[256], sc[256];
  int b = blockIdx.x, t = threadIdx.x;
  int bs = bstart[b], be = bstart[b + 1];
  cnt[t] = 0;
  __syncthreads();
  for (int i = bs + t; i < be; i += 256) atomicAdd(&cnt[bbuf[i] >> 24], 1);
  __syncthreads();
  int v = cnt[t];
  sc[t] = v;
  __syncthreads();
  for (int off = 1; off < 256; off <<= 1) {
    int u = (t >= off) ? sc[t - off] : 0;
    __syncthreads();
    sc[t] += u;
    __syncthreads();
  }
  int ex = sc[t] - v;
  int node = b * 256 + t;
  if (node < nN) row_start[node] = bs + ex;
  cur[t] = ex;
  __syncthreads();
  for (int i = bs + t; i < be; i += 256) {
    unsigned e = bbuf[i];
    int p = atomicAdd(&cur[e >> 24], 1);
    csr_src[bs + p] = (int)(e & 0xFFFFFFu);
  }
}

// ---- fragment-major bf16 weight conversion + x->bf16 mirror ----
__global__ void prep_all(const float* __restrict__ wl, const float* __restrict__ wr,
                         const float* __restrict__ aw, const float* __restrict__ w1,
                         const float* __restrict__ w2, const float* __restrict__ x,
                         unsigned short* __restrict__ wcatf, unsigned short* __restrict__ awbf,
                         unsigned short* __restrict__ w1f, unsigned short* __restrict__ w2f,
                         unsigned short* __restrict__ xb, int nl, int n4) {
  int i = blockIdx.x * 256 + threadIdx.x;
  int tot = nl * 12288;
  int wtot = tot + 4096 + 16384 + 16384;
  if (i < tot) {
    int l = i / 12288, r = i % 12288;
    int e = r & 7, lane = (r >> 3) & 63, idx = r >> 9;  // idx = ft*6+ks (0..23)
    int ft = idx / 6, ks = idx % 6;
    int f = ft * 16 + (lane & 15);
    int k = ks * 32 + (lane >> 4) * 8 + e;
    float v = (k < 128) ? wl[l * 8192 + f * 128 + k] : wr[l * 4096 + f * 64 + (k - 128)];
    wcatf[i] = f2bf(v);
  } else if (i < wtot) {
    int j = i - tot;
    if (j < 4096) {  // awbf: idx = ft*2+k2
      int e = j & 7, lane = (j >> 3) & 63, idx = j >> 9;
      int f = (idx >> 1) * 16 + (lane & 15);
      int k = (idx & 1) * 32 + (lane >> 4) * 8 + e;
      awbf[j] = f2bf(aw[f * 64 + k]);
    } else if (j < 4096 + 16384) {  // w1f: idx = ptg*2+ks
      int q = j - 4096;
      int e = q & 7, lane = (q >> 3) & 63, idx = q >> 9;
      int p = (idx >> 1) * 16 + (lane & 15);
      int k = (idx & 1) * 32 + (lane >> 4) * 8 + e;
      w1f[q] = f2bf(w1[p * 64 + k]);
    } else {  // w2f: idx = ft*8+ks
      int q = j - 20480;
      int e = q & 7, lane = (q >> 3) & 63, idx = q >> 9;
      int f = (idx >> 3) * 16 + (lane & 15);
      int k = (idx & 7) * 32 + (lane >> 4) * 8 + e;
      w2f[q] = f2bf(w2[f * 256 + k]);
    }
  } else {
    int q = i - wtot;
    if (q < n4) {
      float4 v = ((const float4*)x)[q];
      ushort4 o;
      o.x = f2bf(v.x); o.y = f2bf(v.y); o.z = f2bf(v.z); o.w = f2bf(v.w);
      ((ushort4*)xb)[q] = o;
    }
  }
}

// ---- fused SAGE layer: shfl gather + MFMA GEMM + in-wave LN ----
// Block 256 (4 waves), 64 nodes. aggU[64][68]dw (17 quads odd); x A-frags
// direct from bf16 mirror. 7 blocks/CU (VGPR cap 73 -> no spill).
template <bool FIRST>
__global__ __launch_bounds__(256, 7) void sage_layer(
    const float* __restrict__ inf, const unsigned short* __restrict__ inb,
    float* __restrict__ outf, unsigned short* __restrict__ outb,
    const int* __restrict__ row_start, const int* __restrict__ csr_src,
    const unsigned short* __restrict__ wcatf,  // frag-major [24][64][8]
    const unsigned short* __restrict__ awbf,   // frag-major [8][64][8]
    const float* __restrict__ bl, const float* __restrict__ ab,
    const float* __restrict__ lng, const float* __restrict__ lnb,
    int nN, int wf32) {
  __shared__ unsigned aggU[64 * 68];

  int t = threadIdx.x;
  int wv = __builtin_amdgcn_readfirstlane(t >> 6);
  int lane = t & 63;
  int g_lane = lane >> 4;
  int fq4 = (lane & 15) * 4;
  int foff = fq4 * 2;
  int base = blockIdx.x * 64;
  int wn0 = base + wv * 16;

  int rlv = row_start[min(wn0 + min(lane, 16), nN)];
  int rs[17];
#pragma unroll
  for (int i = 0; i <= 16; ++i) rs[i] = __builtin_amdgcn_readlane(rlv, i);

  int offL[4], dgL[4], dgmL[4];
#pragma unroll
  for (int G = 0; G < 4; ++G) {
    int a_ = __shfl(rlv, 4 * G + g_lane);
    int b_ = __shfl(rlv, 4 * G + g_lane + 1);
    offL[G] = a_ - rs[4 * G];
    dgL[G] = b_ - a_;
    dgmL[G] = max(dgL[G] - 1, 0);
  }

  int ivA[4], ivB[4];
#pragma unroll
  for (int G = 0; G < 4; ++G) {
    int Eg = rs[4 * G];
    int lenm1 = max(rs[4 * G + 4] - Eg - 1, 0);
    ivA[G] = min((unsigned)csr_src[Eg + min(lane, lenm1)], (unsigned)(nN - 1));
    ivB[G] = min((unsigned)csr_src[Eg + min(lane + 64, lenm1)], (unsigned)(nN - 1));
  }

  // gather (bf16 mirror): 4 nodes lockstep, 16-edge batches
#pragma unroll
  for (int G = 0; G < 4; ++G) {
    int Eg = rs[4 * G];
    int len = rs[4 * G + 4] - Eg;
    int d0 = rs[4 * G + 1] - rs[4 * G + 0], d1 = rs[4 * G + 2] - rs[4 * G + 1];
    int d2 = rs[4 * G + 3] - rs[4 * G + 2], d3 = rs[4 * G + 4] - rs[4 * G + 3];
    int mm = max(max(d0, d1), max(d2, d3));
    int offl = offL[G], dgl = dgL[G], dgml = dgmL[G];
    float4 mx = make_float4(-INFF, -INFF, -INFF, -INFF);
    float4 sm = make_float4(0.f, 0.f, 0.f, 0.f);

    if (len <= 64) {
      for (int tt = 0; tt < mm; tt += 16) {
        uint2 v[16];
#pragma unroll
        for (int u = 0; u < 16; ++u) {
          int p = offl + min(tt + u, dgml);
          int si = __shfl(ivA[G], p);
          v[u] = *(const uint2*)((const char*)inb + ((si << 7) + foff));
        }
#pragma unroll
        for (int u = 0; u < 16; ++u) {
          float f0 = bf_lo(v[u].x), f1 = bf_hi(v[u].x);
          float f2 = bf_lo(v[u].y), f3 = bf_hi(v[u].y);
          float m = (tt + u < dgl) ? 1.f : 0.f;
          mx.x = fmaxf(mx.x, f0); mx.y = fmaxf(mx.y, f1);
          mx.z = fmaxf(mx.z, f2); mx.w = fmaxf(mx.w, f3);
          sm.x = fmaf(f0, m, sm.x); sm.y = fmaf(f1, m, sm.y);
          sm.z = fmaf(f2, m, sm.z); sm.w = fmaf(f3, m, sm.w);
        }
      }
    } else if (len <= 128) {
      for (int tt = 0; tt < mm; tt += 8) {
        uint2 v[8];
#pragma unroll
        for (int u = 0; u < 8; ++u) {
          int p = offl + min(tt + u, dgml);
          int a = __shfl(ivA[G], p & 63);
          int b = __shfl(ivB[G], p & 63);
          int si = (p < 64) ? a : b;
          v[u] = *(const uint2*)((const char*)inb + ((si << 7) + foff));
        }
#pragma unroll
        for (int u = 0; u < 8; ++u) {
          float f0 = bf_lo(v[u].x), f1 = bf_hi(v[u].x);
          float f2 = bf_lo(v[u].y), f3 = bf_hi(v[u].y);
          float m = (tt + u < dgl) ? 1.f : 0.f;
          mx.x = fmaxf(mx.x, f0); mx.y = fmaxf(mx.y, f1);
          mx.z = fmaxf(mx.z, f2); mx.w = fmaxf(mx.w, f3);
          sm.x = fmaf(f0, m, sm.x); sm.y = fmaf(f1, m, sm.y);
          sm.z = fmaf(f2, m, sm.z); sm.w = fmaf(f3, m, sm.w);
        }
      }
    } else {
      for (int tt = 0; tt < mm; tt += 4) {
        uint2 v[4];
#pragma unroll
        for (int u = 0; u < 4; ++u) {
          int p = offl + min(tt + u, dgml);
          unsigned si = min((unsigned)csr_src[Eg + p], (unsigned)(nN - 1));
          v[u] = *(const uint2*)((const char*)inb + (((int)si << 7) + foff));
        }
#pragma unroll
        for (int u = 0; u < 4; ++u) {
          float f0 = bf_lo(v[u].x), f1 = bf_hi(v[u].x);
          float f2 = bf_lo(v[u].y), f3 = bf_hi(v[u].y);
          float m = (tt + u < dgl) ? 1.f : 0.f;
          mx.x = fmaxf(mx.x, f0); mx.y = fmaxf(mx.y, f1);
          mx.z = fmaxf(mx.z, f2); mx.w = fmaxf(mx.w, f3);
          sm.x = fmaf(f0, m, sm.x); sm.y = fmaf(f1, m, sm.y);
          sm.z = fmaf(f2, m, sm.z); sm.w = fmaf(f3, m, sm.w);
        }
      }
    }

    int rowU = (wv * 16 + G * 4 + g_lane) * 68;
    float ok = (dgl > 0) ? 1.f : 0.f;
    float r = 1.f / (float)max(dgl, 1);
    aggU[rowU + (fq4 >> 1)] = pack2(ok * mx.x, ok * mx.y);
    aggU[rowU + (fq4 >> 1) + 1] = pack2(ok * mx.z, ok * mx.w);
    aggU[rowU + 32 + (fq4 >> 1)] = pack2(sm.x * r, sm.y * r);
    aggU[rowU + 32 + (fq4 >> 1) + 1] = pack2(sm.z * r, sm.w * r);
  }
  __syncthreads();

  // ---- MFMA GEMM: wave = node-tile wv; acc[ft] covers f-tiles 0..3 ----
  int ml = lane & 15, gq = lane >> 4;
  bf16x8 afr[6];
  const char* arow = (const char*)aggU + (size_t)(wv * 16 + ml) * 272;
  afr[0] = *(const bf16x8*)(arow + gq * 16);
  afr[1] = *(const bf16x8*)(arow + 64 + gq * 16);
  afr[2] = *(const bf16x8*)(arow + 128 + gq * 16);
  afr[3] = *(const bf16x8*)(arow + 192 + gq * 16);
  unsigned anode = min((unsigned)(base + wv * 16 + ml), (unsigned)(nN - 1));
  const char* xrow = (const char*)inb + (size_t)anode * 128;
  afr[4] = *(const bf16x8*)(xrow + gq * 16);
  afr[5] = *(const bf16x8*)(xrow + 64 + gq * 16);

  f32x4 acc[4], accr[4];
#pragma unroll
  for (int ft = 0; ft < 4; ++ft) {
    acc[ft] = (f32x4){0.f, 0.f, 0.f, 0.f};
#pragma unroll
    for (int ks = 0; ks < 6; ++ks) {
      bf16x8 b = *(const bf16x8*)(wcatf + ((ft * 6 + ks) << 9) + (lane << 3));
      acc[ft] = __builtin_amdgcn_mfma_f32_16x16x32_bf16(afr[ks], b, acc[ft], 0, 0, 0);
    }
    if (FIRST) {
      accr[ft] = (f32x4){0.f, 0.f, 0.f, 0.f};
#pragma unroll
      for (int k2 = 0; k2 < 2; ++k2) {
        bf16x8 b = *(const bf16x8*)(awbf + ((ft * 2 + k2) << 9) + (lane << 3));
        accr[ft] = __builtin_amdgcn_mfma_f32_16x16x32_bf16(afr[4 + k2], b, accr[ft], 0, 0, 0);
      }
    }
  }

  // ---- epilogue: bias, in-wave LN, residual, SiLU, store ----
  float blv[4], gv[4], bvv[4], abv[4];
#pragma unroll
  for (int ft = 0; ft < 4; ++ft) {
    blv[ft] = bl[ft * 16 + ml];
    gv[ft] = lng[ft * 16 + ml];
    bvv[ft] = lnb[ft * 16 + ml];
    if (FIRST) abv[ft] = ab[ft * 16 + ml];
  }
  float v[4][4];
  float s1[4] = {0.f, 0.f, 0.f, 0.f}, s2[4] = {0.f, 0.f, 0.f, 0.f};
#pragma unroll
  for (int ft = 0; ft < 4; ++ft)
#pragma unroll
    for (int reg = 0; reg < 4; ++reg) {
      float a = acc[ft][reg] + blv[ft];
      v[ft][reg] = a;
      s1[reg] += a;
      s2[reg] = fmaf(a, a, s2[reg]);
    }
#pragma unroll
  for (int m = 1; m < 16; m <<= 1)
#pragma unroll
    for (int reg = 0; reg < 4; ++reg) {
      s1[reg] += __shfl_xor(s1[reg], m);
      s2[reg] += __shfl_xor(s2[reg], m);
    }

#pragma unroll
  for (int reg = 0; reg < 4; ++reg) {
    float mean = s1[reg] * 0.015625f;
    float var = s2[reg] * 0.015625f - mean * mean;
    float rs_ = rsqrtf(var + 1e-5f);
    int nj = base + wv * 16 + gq * 4 + reg;
    unsigned njc = min((unsigned)nj, (unsigned)(nN - 1));
    bool ok = nj < nN;
#pragma unroll
    for (int ft = 0; ft < 4; ++ft) {
      float res = FIRST ? (accr[ft][reg] + abv[ft])
                        : inf[(size_t)njc * 64 + ft * 16 + ml];
      float y = (v[ft][reg] - mean) * rs_ * gv[ft] + bvv[ft] + res;
      float h = y / (1.f + __expf(-y));
      if (ok) {
        if (wf32) outf[(size_t)nj * 64 + ft * 16 + ml] = h;
        outb[(size_t)nj * 64 + ft * 16 + ml] = f2bf(h);
      }
    }
  }
}

// ---- MLP head (v15): frag-major weights ----
__global__ __launch_bounds__(512) void mlp_head(
    const unsigned short* __restrict__ inb, float* __restrict__ out,
    const unsigned short* __restrict__ w1f, const float* __restrict__ b1,
    const float* __restrict__ lng, const float* __restrict__ lnb,
    const unsigned short* __restrict__ w2f, const float* __restrict__ b2, int nN) {
  __shared__ unsigned short up[64 * 264];
  __shared__ float ln1[128], ln2[128];

  int t = threadIdx.x;
  int wv = __builtin_amdgcn_readfirstlane(t >> 6);
  int lane = t & 63;
  int ml = lane & 15, gq = lane >> 4;
  int base = blockIdx.x * 64;
  int nt = wv & 3, ph = wv >> 2;

  int nodeA = min(base + nt * 16 + ml, nN - 1);
  const char* arow = (const char*)inb + (size_t)nodeA * 128;
  bf16x8 a0 = *(const bf16x8*)(arow + gq * 16);
  bf16x8 a1 = *(const bf16x8*)(arow + 64 + gq * 16);

  f32x4 acc[8];
#pragma unroll
  for (int pt = 0; pt < 8; ++pt) {
    int ptg = ph * 8 + pt;
    bf16x8 b0 = *(const bf16x8*)(w1f + ((ptg * 2 + 0) << 9) + (lane << 3));
    bf16x8 b1fr = *(const bf16x8*)(w1f + ((ptg * 2 + 1) << 9) + (lane << 3));
    f32x4 c = (f32x4){0.f, 0.f, 0.f, 0.f};
    c = __builtin_amdgcn_mfma_f32_16x16x32_bf16(a0, b0, c, 0, 0, 0);
    c = __builtin_amdgcn_mfma_f32_16x16x32_bf16(a1, b1fr, c, 0, 0, 0);
    acc[pt] = c;
  }

  float s1[4] = {0.f, 0.f, 0.f, 0.f}, s2[4] = {0.f, 0.f, 0.f, 0.f};
#pragma unroll
  for (int pt = 0; pt < 8; ++pt) {
    float bb = b1[ph * 128 + pt * 16 + ml];
#pragma unroll
    for (int reg = 0; reg < 4; ++reg) {
      float u = acc[pt][reg] + bb;
      u = u / (1.f + __expf(-u));
      acc[pt][reg] = u;
      s1[reg] += u;
      s2[reg] = fmaf(u, u, s2[reg]);
    }
  }
#pragma unroll
  for (int m = 1; m < 16; m <<= 1)
#pragma unroll
    for (int reg = 0; reg < 4; ++reg) {
      s1[reg] += __shfl_xor(s1[reg], m);
      s2[reg] += __shfl_xor(s2[reg], m);
    }
  if (ml == 0) {
#pragma unroll
    for (int reg = 0; reg < 4; ++reg) {
      ln1[wv * 16 + gq * 4 + reg] = s1[reg];
      ln2[wv * 16 + gq * 4 + reg] = s2[reg];
    }
  }
  __syncthreads();
  float mean[4], rsv[4];
#pragma unroll
  for (int reg = 0; reg < 4; ++reg) {
    float t1 = s1[reg] + ln1[(wv ^ 4) * 16 + gq * 4 + reg];
    float t2 = s2[reg] + ln2[(wv ^ 4) * 16 + gq * 4 + reg];
    float mn = t1 * 0.00390625f;
    float var = t2 * 0.00390625f - mn * mn;
    mean[reg] = mn;
    rsv[reg] = rsqrtf(var + 1e-5f);
  }
#pragma unroll
  for (int pt = 0; pt < 8; ++pt) {
    int p = ph * 128 + pt * 16 + ml;
    float gg = lng[p], bb = lnb[p];
#pragma unroll
    for (int reg = 0; reg < 4; ++reg) {
      float val = (acc[pt][reg] - mean[reg]) * rsv[reg] * gg + bb;
      up[(nt * 16 + gq * 4 + reg) * 264 + p] = f2bf(val);
    }
  }
  __syncthreads();

  f32x4 o0 = (f32x4){0.f, 0.f, 0.f, 0.f};
  f32x4 o1 = (f32x4){0.f, 0.f, 0.f, 0.f};
  const char* urow = (const char*)up + (size_t)(nt * 16 + ml) * 528;
  int ftA = ph * 2, ftB = ph * 2 + 1;
#pragma unroll
  for (int ks = 0; ks < 8; ++ks) {
    bf16x8 a = *(const bf16x8*)(urow + ks * 64 + gq * 16);
    bf16x8 bA = *(const bf16x8*)(w2f + ((ftA * 8 + ks) << 9) + (lane << 3));
    bf16x8 bB = *(const bf16x8*)(w2f + ((ftB * 8 + ks) << 9) + (lane << 3));
    o0 = __builtin_amdgcn_mfma_f32_16x16x32_bf16(a, bA, o0, 0, 0, 0);
    o1 = __builtin_amdgcn_mfma_f32_16x16x32_bf16(a, bB, o1, 0, 0, 0);
  }
  float b2A = b2[ftA * 16 + ml], b2B = b2[ftB * 16 + ml];
#pragma unroll
  for (int reg = 0; reg < 4; ++reg) {
    int nj = base + nt * 16 + gq * 4 + reg;
    if (nj < nN) {
      out[(size_t)nj * 64 + ftA * 16 + ml] = o0[reg] + b2A;
      out[(size_t)nj * 64 + ftB * 16 + ml] = o1[reg] + b2B;
    }
  }
}

extern "C" void kernel_launch(void* const* d_in, const int* in_sizes, int n_in,
                              void* d_out, int out_size, void* d_ws, size_t ws_size,
                              hipStream_t stream) {
  const float* x = (const float*)d_in[0];
  const void* edges = d_in[1];
  const float* conv_wl = (const float*)d_in[2];
  const float* conv_bl = (const float*)d_in[3];
  const float* conv_wr = (const float*)d_in[4];
  const float* ln_g = (const float*)d_in[5];
  const float* ln_b = (const float*)d_in[6];
  const float* adapter_w = (const float*)d_in[7];
  const float* adapter_b = (const float*)d_in[8];
  const float* mlp_w1 = (const float*)d_in[9];
  const float* mlp_b1 = (const float*)d_in[10];
  const float* mlp_lng = (const float*)d_in[11];
  const float* mlp_lnb = (const float*)d_in[12];
  const float* mlp_w2 = (const float*)d_in[13];
  const float* mlp_b2 = (const float*)d_in[14];

  const int N = in_sizes[0] / 64;
  const int E = in_sizes[1] / 2;
  const int NL = in_sizes[2] / (64 * 128);  // 5

  const int Na = (N + 63) & ~63;
  const int Ea = (E + 63) & ~63;
  const int nbk = (N + 255) / 256;

  int* row_start = (int*)d_ws;
  int* csr_src = row_start + (Na + 64);
  int* bcnt = csr_src + (Ea + 256);
  int* bstart = bcnt + (nbk + 8);
  int* bcursor = bstart + (nbk + 8);
  unsigned short* wcatf = (unsigned short*)(bcursor + (nbk + 8));
  unsigned short* awbf = wcatf + (size_t)NL * 12288;
  unsigned short* w1f = awbf + 4096;
  unsigned short* w2f = w1f + 16384;
  unsigned short* b0 = w2f + 16384;
  unsigned short* b1m = b0 + (size_t)Na * 64;
  unsigned* bbuf = (unsigned*)b1m;  // alias: bbuf dead before layer 0 writes b1m
  float* outf = (float*)d_out;

  hipMemsetAsync(bcnt, 0, (size_t)(nbk + 8) * 4, stream);

  bucket_count<<<512, 256, 0, stream>>>(edges, bcnt, E, nbk);
  bucket_scan<<<1, 512, 0, stream>>>(bcnt, bstart, bcursor, row_start, nbk, E, N);
  const int chunk = 256 * SCH;
  const int nsb2 = (E + chunk - 1) / chunk;
  bucket_scatter<<<nsb2, 256, 0, stream>>>(edges, bcursor, bbuf, E, nbk);
  bucket_to_csr<<<nbk, 256, 0, stream>>>(bbuf, bstart, row_start, csr_src, N);

  int prep_tot = NL * 12288 + 4096 + 16384 + 16384;
  int n4 = N * 16;
  int prep_blocks = (prep_tot + n4 + 255) / 256;
  prep_all<<<prep_blocks, 256, 0, stream>>>(conv_wl, conv_wr, adapter_w, mlp_w1, mlp_w2,
                                            x, wcatf, awbf, w1f, w2f, b0, NL, n4);

  const int nb = (N + 63) / 64;
  for (int i = 0; i < NL; ++i) {
    const float* inf = (i == 0) ? x : outf;
    unsigned short* inb = (i & 1) ? b1m : b0;
    unsigned short* outb = (i & 1) ? b0 : b1m;
    const unsigned short* wc = wcatf + (size_t)i * 12288;
    const float* bl = conv_bl + (size_t)i * 64;
    const float* g = ln_g + (size_t)i * 64;
    const float* b = ln_b + (size_t)i * 64;
    int wf32 = (i == NL - 1) ? 0 : 1;
    if (i == 0) {
      sage_layer<true><<<nb, 256, 0, stream>>>(inf, inb, outf, outb, row_start, csr_src,
                                               wc, awbf, bl, adapter_b, g, b, N, wf32);
    } else {
      sage_layer<false><<<nb, 256, 0, stream>>>(inf, inb, outf, outb, row_start, csr_src,
                                                wc, awbf, bl, adapter_b, g, b, N, wf32);
    }
  }
  unsigned short* hb_final = ((NL - 1) & 1) ? b0 : b1m;
  mlp_head<<<nb, 512, 0, stream>>>(hb_final, outf, w1f, mlp_b1, mlp_lng, mlp_lnb,
                                   w2f, mlp_b2, N);
}

// Round 18
// 337.359 us; speedup vs baseline: 1.1971x; 1.0727x over previous
//
#include <hip/hip_runtime.h>

// SAGEEncoder v18 == v15 (best measured, 337.8us): frag-major MFMA weights,
// sage 6 blk/CU (x staged in LDS, 84-VGPR budget -> no spill),
// radix-bucket CSR build, v13 mlp_head. Occupancy levers at 7/8 blk/CU
// proven net-negative (r10/r16/r17: gather batch spills below ~84 VGPRs).

#define INFF 3.402823466e38f

typedef __attribute__((ext_vector_type(8))) short bf16x8;
typedef __attribute__((ext_vector_type(4))) float f32x4;

__device__ __forceinline__ unsigned short f2bf(float f) {
  unsigned u = __float_as_uint(f);
  u = (u + 0x7FFFu + ((u >> 16) & 1u)) >> 16;
  return (unsigned short)u;
}
__device__ __forceinline__ unsigned pack2(float a, float b) {
  return (unsigned)f2bf(a) | ((unsigned)f2bf(b) << 16);
}
__device__ __forceinline__ float bf_lo(unsigned u) { return __uint_as_float(u << 16); }
__device__ __forceinline__ float bf_hi(unsigned u) { return __uint_as_float(u & 0xFFFF0000u); }

// int64 iff the first 32 odd u32 slots are all zero
__device__ __forceinline__ int detect64(const unsigned* __restrict__ e) {
  int is64 = 1;
#pragma unroll
  for (int i = 0; i < 32; ++i) is64 &= (e[2 * i + 1] == 0u) ? 1 : 0;
  return is64;
}

__device__ __forceinline__ int edge_val(const void* e, int is64, long long idx) {
  if (is64) return (int)((const long long*)e)[idx];
  return ((const int*)e)[idx];
}

// ---- radix-bucket CSR build (buckets of 256 nodes by dst>>8) ----
__global__ void bucket_count(const void* __restrict__ edges, int* __restrict__ bcnt,
                             int nE, int nbk) {
  __shared__ int h[512];
  int t = threadIdx.x;
  for (int i = t; i < nbk; i += 256) h[i] = 0;
  __syncthreads();
  int is64 = detect64((const unsigned*)edges);
  long long E = nE;
  for (int i = blockIdx.x * 256 + t; i < nE; i += gridDim.x * 256) {
    int dst = edge_val(edges, is64, E + i);
    atomicAdd(&h[dst >> 8], 1);
  }
  __syncthreads();
  for (int i = t; i < nbk; i += 256) {
    int v = h[i];
    if (v) atomicAdd(&bcnt[i], v);
  }
}

// single block: exclusive scan of bcnt[nbk] (nbk <= 512)
__global__ void bucket_scan(const int* __restrict__ bcnt, int* __restrict__ bstart,
                            int* __restrict__ bcursor, int* __restrict__ row_start,
                            int nbk, int nE, int nN) {
  __shared__ int s[512];
  int t = threadIdx.x;
  int v = (t < nbk) ? bcnt[t] : 0;
  s[t] = v;
  __syncthreads();
  for (int off = 1; off < 512; off <<= 1) {
    int u = (t >= off) ? s[t - off] : 0;
    __syncthreads();
    s[t] += u;
    __syncthreads();
  }
  if (t < nbk) {
    int ex = s[t] - v;
    bstart[t] = ex;
    bcursor[t] = ex;
  }
  if (t == 0) {
    bstart[nbk] = nE;
    row_start[nN] = nE;
  }
}

// block-aggregated scatter: LDS histogram -> 1 cursor atomic per bucket per
// block -> LDS-cursor scatter into dense reserved ranges.
#define SCH 16  // edges per thread per chunk (chunk = 4096)
__global__ __launch_bounds__(256) void bucket_scatter(
    const void* __restrict__ edges, int* __restrict__ bcursor,
    unsigned* __restrict__ bbuf, int nE, int nbk) {
  __shared__ int cnt[512];
  __shared__ int basep[512];
  int t = threadIdx.x;
  int is64 = detect64((const unsigned*)edges);
  long long E = nE;
  const int chunk = 256 * SCH;
  for (int c0 = blockIdx.x * chunk; c0 < nE; c0 += gridDim.x * chunk) {
    for (int i = t; i < nbk; i += 256) cnt[i] = 0;
    __syncthreads();
    unsigned pk[SCH];
    short bk[SCH];
#pragma unroll
    for (int u = 0; u < SCH; ++u) {
      int i = c0 + u * 256 + t;  // coalesced
      if (i < nE) {
        int src = edge_val(edges, is64, i);
        int dst = edge_val(edges, is64, E + i);
        pk[u] = ((unsigned)(dst & 255) << 24) | (unsigned)src;
        bk[u] = (short)(dst >> 8);
        atomicAdd(&cnt[bk[u]], 1);
      } else {
        bk[u] = -1;
      }
    }
    __syncthreads();
    for (int i = t; i < nbk; i += 256) {
      int c = cnt[i];
      basep[i] = c ? atomicAdd(&bcursor[i], c) : 0;
    }
    __syncthreads();
    for (int i = t; i < nbk; i += 256) cnt[i] = 0;
    __syncthreads();
#pragma unroll
    for (int u = 0; u < SCH; ++u) {
      if (bk[u] >= 0) {
        int local = atomicAdd(&cnt[bk[u]], 1);
        bbuf[basep[bk[u]] + local] = pk[u];
      }
    }
    __syncthreads();
  }
}

// one block per bucket: LDS histogram+scan -> row_start; local scatter -> csr_src
__global__ __launch_bounds__(256) void bucket_to_csr(
    const unsigned* __restrict__ bbuf, const int* __restrict__ bstart,
    int* __restrict__ row_start, int* __restrict__ csr_src, int nN) {
  __shared__ int cnt[256], cur[256], sc[256];
  int b = blockIdx.x, t = threadIdx.x;
  int bs = bstart[b], be = bstart[b + 1];
  cnt[t] = 0;
  __syncthreads();
  for (int i = bs + t; i < be; i += 256) atomicAdd(&cnt[bbuf[i] >> 24], 1);
  __syncthreads();
  int v = cnt[t];
  sc[t] = v;
  __syncthreads();
  for (int off = 1; off < 256; off <<= 1) {
    int u = (t >= off) ? sc[t - off] : 0;
    __syncthreads();
    sc[t] += u;
    __syncthreads();
  }
  int ex = sc[t] - v;
  int node = b * 256 + t;
  if (node < nN) row_start[node] = bs + ex;
  cur[t] = ex;
  __syncthreads();
  for (int i = bs + t; i < be; i += 256) {
    unsigned e = bbuf[i];
    int p = atomicAdd(&cur[e >> 24], 1);
    csr_src[bs + p] = (int)(e & 0xFFFFFFu);
  }
}

// ---- fragment-major bf16 weight conversion + x->bf16 mirror ----
// B-frag for mfma_16x16x32: lane l -> row f=tile*16+(l&15), k=ks*32+(l>>4)*8+e.
// Stored as w[tileks][lane][8] so a wave's load is contiguous 1KB.
__global__ void prep_all(const float* __restrict__ wl, const float* __restrict__ wr,
                         const float* __restrict__ aw, const float* __restrict__ w1,
                         const float* __restrict__ w2, const float* __restrict__ x,
                         unsigned short* __restrict__ wcatf, unsigned short* __restrict__ awbf,
                         unsigned short* __restrict__ w1f, unsigned short* __restrict__ w2f,
                         unsigned short* __restrict__ xb, int nl, int n4) {
  int i = blockIdx.x * 256 + threadIdx.x;
  int tot = nl * 12288;
  int wtot = tot + 4096 + 16384 + 16384;
  if (i < tot) {
    int l = i / 12288, r = i % 12288;
    int e = r & 7, lane = (r >> 3) & 63, idx = r >> 9;  // idx = ft*6+ks (0..23)
    int ft = idx / 6, ks = idx % 6;
    int f = ft * 16 + (lane & 15);
    int k = ks * 32 + (lane >> 4) * 8 + e;
    float v = (k < 128) ? wl[l * 8192 + f * 128 + k] : wr[l * 4096 + f * 64 + (k - 128)];
    wcatf[i] = f2bf(v);
  } else if (i < wtot) {
    int j = i - tot;
    if (j < 4096) {  // awbf: idx = ft*2+k2 (0..7)
      int e = j & 7, lane = (j >> 3) & 63, idx = j >> 9;
      int f = (idx >> 1) * 16 + (lane & 15);
      int k = (idx & 1) * 32 + (lane >> 4) * 8 + e;
      awbf[j] = f2bf(aw[f * 64 + k]);
    } else if (j < 4096 + 16384) {  // w1f: idx = ptg*2+ks (0..31)
      int q = j - 4096;
      int e = q & 7, lane = (q >> 3) & 63, idx = q >> 9;
      int p = (idx >> 1) * 16 + (lane & 15);
      int k = (idx & 1) * 32 + (lane >> 4) * 8 + e;
      w1f[q] = f2bf(w1[p * 64 + k]);
    } else {  // w2f: idx = ft*8+ks (0..31)
      int q = j - 20480;
      int e = q & 7, lane = (q >> 3) & 63, idx = q >> 9;
      int f = (idx >> 3) * 16 + (lane & 15);
      int k = (idx & 7) * 32 + (lane >> 4) * 8 + e;
      w2f[q] = f2bf(w2[f * 256 + k]);
    }
  } else {
    int q = i - wtot;
    if (q < n4) {
      float4 v = ((const float4*)x)[q];
      ushort4 o;
      o.x = f2bf(v.x); o.y = f2bf(v.y); o.z = f2bf(v.z); o.w = f2bf(v.w);
      ((ushort4*)xb)[q] = o;
    }
  }
}

// ---- fused SAGE layer (v13/v15): shfl gather + MFMA GEMM + in-wave LN ----
template <bool FIRST>
__global__ __launch_bounds__(256, 6) void sage_layer(
    const float* __restrict__ inf, const unsigned short* __restrict__ inb,
    float* __restrict__ outf, unsigned short* __restrict__ outb,
    const int* __restrict__ row_start, const int* __restrict__ csr_src,
    const unsigned short* __restrict__ wcatf,  // frag-major [24][64][8]
    const unsigned short* __restrict__ awbf,   // frag-major [8][64][8]
    const float* __restrict__ bl, const float* __restrict__ ab,
    const float* __restrict__ lng, const float* __restrict__ lnb,
    int nN, int wf32) {
  __shared__ unsigned aggU[64 * 100];

  int t = threadIdx.x;
  int wv = __builtin_amdgcn_readfirstlane(t >> 6);
  int lane = t & 63;
  int g_lane = lane >> 4;
  int fq4 = (lane & 15) * 4;
  int foff = fq4 * 2;
  int base = blockIdx.x * 64;
  int wn0 = base + wv * 16;

  int rlv = row_start[min(wn0 + min(lane, 16), nN)];
  int rs[17];
#pragma unroll
  for (int i = 0; i <= 16; ++i) rs[i] = __builtin_amdgcn_readlane(rlv, i);

  int offL[4], dgL[4], dgmL[4];
#pragma unroll
  for (int G = 0; G < 4; ++G) {
    int a_ = __shfl(rlv, 4 * G + g_lane);
    int b_ = __shfl(rlv, 4 * G + g_lane + 1);
    offL[G] = a_ - rs[4 * G];
    dgL[G] = b_ - a_;
    dgmL[G] = max(dgL[G] - 1, 0);
  }

  int ivA[4], ivB[4];
#pragma unroll
  for (int G = 0; G < 4; ++G) {
    int Eg = rs[4 * G];
    int lenm1 = max(rs[4 * G + 4] - Eg - 1, 0);
    ivA[G] = min((unsigned)csr_src[Eg + min(lane, lenm1)], (unsigned)(nN - 1));
    ivB[G] = min((unsigned)csr_src[Eg + min(lane + 64, lenm1)], (unsigned)(nN - 1));
  }

  // stage self rows (fp32 -> bf16, cols 128..191)
#pragma unroll
  for (int R = 0; R < 4; ++R) {
    int nloc = R * 4 + g_lane;
    int nj = wn0 + nloc;
    bool ok = nj < nN;
    unsigned njc = min((unsigned)nj, (unsigned)(nN - 1));
    float4 xv = *(const float4*)(inf + (size_t)njc * 64u + fq4);
    if (!ok) xv = make_float4(0.f, 0.f, 0.f, 0.f);
    int rowU = (wv * 16 + nloc) * 100;
    aggU[rowU + 64 + (fq4 >> 1)] = pack2(xv.x, xv.y);
    aggU[rowU + 64 + (fq4 >> 1) + 1] = pack2(xv.z, xv.w);
  }

  // gather (bf16 mirror): 4 nodes lockstep, 16-edge batches
#pragma unroll
  for (int G = 0; G < 4; ++G) {
    int Eg = rs[4 * G];
    int len = rs[4 * G + 4] - Eg;
    int d0 = rs[4 * G + 1] - rs[4 * G + 0], d1 = rs[4 * G + 2] - rs[4 * G + 1];
    int d2 = rs[4 * G + 3] - rs[4 * G + 2], d3 = rs[4 * G + 4] - rs[4 * G + 3];
    int mm = max(max(d0, d1), max(d2, d3));
    int offl = offL[G], dgl = dgL[G], dgml = dgmL[G];
    float4 mx = make_float4(-INFF, -INFF, -INFF, -INFF);
    float4 sm = make_float4(0.f, 0.f, 0.f, 0.f);

    if (len <= 64) {
      for (int tt = 0; tt < mm; tt += 16) {
        uint2 v[16];
#pragma unroll
        for (int u = 0; u < 16; ++u) {
          int p = offl + min(tt + u, dgml);
          int si = __shfl(ivA[G], p);
          v[u] = *(const uint2*)((const char*)inb + ((si << 7) + foff));
        }
#pragma unroll
        for (int u = 0; u < 16; ++u) {
          float f0 = bf_lo(v[u].x), f1 = bf_hi(v[u].x);
          float f2 = bf_lo(v[u].y), f3 = bf_hi(v[u].y);
          float m = (tt + u < dgl) ? 1.f : 0.f;
          mx.x = fmaxf(mx.x, f0); mx.y = fmaxf(mx.y, f1);
          mx.z = fmaxf(mx.z, f2); mx.w = fmaxf(mx.w, f3);
          sm.x = fmaf(f0, m, sm.x); sm.y = fmaf(f1, m, sm.y);
          sm.z = fmaf(f2, m, sm.z); sm.w = fmaf(f3, m, sm.w);
        }
      }
    } else if (len <= 128) {
      for (int tt = 0; tt < mm; tt += 8) {
        uint2 v[8];
#pragma unroll
        for (int u = 0; u < 8; ++u) {
          int p = offl + min(tt + u, dgml);
          int a = __shfl(ivA[G], p & 63);
          int b = __shfl(ivB[G], p & 63);
          int si = (p < 64) ? a : b;
          v[u] = *(const uint2*)((const char*)inb + ((si << 7) + foff));
        }
#pragma unroll
        for (int u = 0; u < 8; ++u) {
          float f0 = bf_lo(v[u].x), f1 = bf_hi(v[u].x);
          float f2 = bf_lo(v[u].y), f3 = bf_hi(v[u].y);
          float m = (tt + u < dgl) ? 1.f : 0.f;
          mx.x = fmaxf(mx.x, f0); mx.y = fmaxf(mx.y, f1);
          mx.z = fmaxf(mx.z, f2); mx.w = fmaxf(mx.w, f3);
          sm.x = fmaf(f0, m, sm.x); sm.y = fmaf(f1, m, sm.y);
          sm.z = fmaf(f2, m, sm.z); sm.w = fmaf(f3, m, sm.w);
        }
      }
    } else {
      for (int tt = 0; tt < mm; tt += 4) {
        uint2 v[4];
#pragma unroll
        for (int u = 0; u < 4; ++u) {
          int p = offl + min(tt + u, dgml);
          unsigned si = min((unsigned)csr_src[Eg + p], (unsigned)(nN - 1));
          v[u] = *(const uint2*)((const char*)inb + (((int)si << 7) + foff));
        }
#pragma unroll
        for (int u = 0; u < 4; ++u) {
          float f0 = bf_lo(v[u].x), f1 = bf_hi(v[u].x);
          float f2 = bf_lo(v[u].y), f3 = bf_hi(v[u].y);
          float m = (tt + u < dgl) ? 1.f : 0.f;
          mx.x = fmaxf(mx.x, f0); mx.y = fmaxf(mx.y, f1);
          mx.z = fmaxf(mx.z, f2); mx.w = fmaxf(mx.w, f3);
          sm.x = fmaf(f0, m, sm.x); sm.y = fmaf(f1, m, sm.y);
          sm.z = fmaf(f2, m, sm.z); sm.w = fmaf(f3, m, sm.w);
        }
      }
    }

    int rowU = (wv * 16 + G * 4 + g_lane) * 100;
    float ok = (dgl > 0) ? 1.f : 0.f;
    float r = 1.f / (float)max(dgl, 1);
    aggU[rowU + (fq4 >> 1)] = pack2(ok * mx.x, ok * mx.y);
    aggU[rowU + (fq4 >> 1) + 1] = pack2(ok * mx.z, ok * mx.w);
    aggU[rowU + 32 + (fq4 >> 1)] = pack2(sm.x * r, sm.y * r);
    aggU[rowU + 32 + (fq4 >> 1) + 1] = pack2(sm.z * r, sm.w * r);
  }
  __syncthreads();

  // ---- MFMA GEMM: wave = node-tile wv; acc[ft] covers f-tiles 0..3 ----
  int ml = lane & 15, gq = lane >> 4;
  bf16x8 afr[6];
  const char* arow = (const char*)aggU + (size_t)(wv * 16 + ml) * 400;
#pragma unroll
  for (int ks = 0; ks < 6; ++ks)
    afr[ks] = *(const bf16x8*)(arow + ks * 64 + gq * 16);

  f32x4 acc[4], accr[4];
#pragma unroll
  for (int ft = 0; ft < 4; ++ft) {
    acc[ft] = (f32x4){0.f, 0.f, 0.f, 0.f};
#pragma unroll
    for (int ks = 0; ks < 6; ++ks) {
      bf16x8 b = *(const bf16x8*)(wcatf + ((ft * 6 + ks) << 9) + (lane << 3));
      acc[ft] = __builtin_amdgcn_mfma_f32_16x16x32_bf16(afr[ks], b, acc[ft], 0, 0, 0);
    }
    if (FIRST) {
      accr[ft] = (f32x4){0.f, 0.f, 0.f, 0.f};
#pragma unroll
      for (int k2 = 0; k2 < 2; ++k2) {
        bf16x8 b = *(const bf16x8*)(awbf + ((ft * 2 + k2) << 9) + (lane << 3));
        accr[ft] = __builtin_amdgcn_mfma_f32_16x16x32_bf16(afr[4 + k2], b, accr[ft], 0, 0, 0);
      }
    }
  }

  // ---- epilogue: bias, in-wave LN, residual, SiLU, store ----
  float blv[4], gv[4], bvv[4], abv[4];
#pragma unroll
  for (int ft = 0; ft < 4; ++ft) {
    blv[ft] = bl[ft * 16 + ml];
    gv[ft] = lng[ft * 16 + ml];
    bvv[ft] = lnb[ft * 16 + ml];
    if (FIRST) abv[ft] = ab[ft * 16 + ml];
  }
  float v[4][4];
  float s1[4] = {0.f, 0.f, 0.f, 0.f}, s2[4] = {0.f, 0.f, 0.f, 0.f};
#pragma unroll
  for (int ft = 0; ft < 4; ++ft)
#pragma unroll
    for (int reg = 0; reg < 4; ++reg) {
      float a = acc[ft][reg] + blv[ft];
      v[ft][reg] = a;
      s1[reg] += a;
      s2[reg] = fmaf(a, a, s2[reg]);
    }
#pragma unroll
  for (int m = 1; m < 16; m <<= 1)
#pragma unroll
    for (int reg = 0; reg < 4; ++reg) {
      s1[reg] += __shfl_xor(s1[reg], m);
      s2[reg] += __shfl_xor(s2[reg], m);
    }

#pragma unroll
  for (int reg = 0; reg < 4; ++reg) {
    float mean = s1[reg] * 0.015625f;
    float var = s2[reg] * 0.015625f - mean * mean;
    float rs_ = rsqrtf(var + 1e-5f);
    int nj = base + wv * 16 + gq * 4 + reg;
    unsigned njc = min((unsigned)nj, (unsigned)(nN - 1));
    bool ok = nj < nN;
#pragma unroll
    for (int ft = 0; ft < 4; ++ft) {
      float res = FIRST ? (accr[ft][reg] + abv[ft])
                        : inf[(size_t)njc * 64 + ft * 16 + ml];
      float y = (v[ft][reg] - mean) * rs_ * gv[ft] + bvv[ft] + res;
      float h = y / (1.f + __expf(-y));
      if (ok) {
        if (wf32) outf[(size_t)nj * 64 + ft * 16 + ml] = h;
        outb[(size_t)nj * 64 + ft * 16 + ml] = f2bf(h);
      }
    }
  }
}

// ---- MLP head (v13 structure, frag-major weights) ----
__global__ __launch_bounds__(512) void mlp_head(
    const unsigned short* __restrict__ inb, float* __restrict__ out,
    const unsigned short* __restrict__ w1f, const float* __restrict__ b1,
    const float* __restrict__ lng, const float* __restrict__ lnb,
    const unsigned short* __restrict__ w2f, const float* __restrict__ b2, int nN) {
  __shared__ unsigned short up[64 * 264];
  __shared__ float ln1[128], ln2[128];

  int t = threadIdx.x;
  int wv = __builtin_amdgcn_readfirstlane(t >> 6);
  int lane = t & 63;
  int ml = lane & 15, gq = lane >> 4;
  int base = blockIdx.x * 64;
  int nt = wv & 3, ph = wv >> 2;

  int nodeA = min(base + nt * 16 + ml, nN - 1);
  const char* arow = (const char*)inb + (size_t)nodeA * 128;
  bf16x8 a0 = *(const bf16x8*)(arow + gq * 16);
  bf16x8 a1 = *(const bf16x8*)(arow + 64 + gq * 16);

  f32x4 acc[8];
#pragma unroll
  for (int pt = 0; pt < 8; ++pt) {
    int ptg = ph * 8 + pt;
    bf16x8 b0 = *(const bf16x8*)(w1f + ((ptg * 2 + 0) << 9) + (lane << 3));
    bf16x8 b1fr = *(const bf16x8*)(w1f + ((ptg * 2 + 1) << 9) + (lane << 3));
    f32x4 c = (f32x4){0.f, 0.f, 0.f, 0.f};
    c = __builtin_amdgcn_mfma_f32_16x16x32_bf16(a0, b0, c, 0, 0, 0);
    c = __builtin_amdgcn_mfma_f32_16x16x32_bf16(a1, b1fr, c, 0, 0, 0);
    acc[pt] = c;
  }

  float s1[4] = {0.f, 0.f, 0.f, 0.f}, s2[4] = {0.f, 0.f, 0.f, 0.f};
#pragma unroll
  for (int pt = 0; pt < 8; ++pt) {
    float bb = b1[ph * 128 + pt * 16 + ml];
#pragma unroll
    for (int reg = 0; reg < 4; ++reg) {
      float u = acc[pt][reg] + bb;
      u = u / (1.f + __expf(-u));
      acc[pt][reg] = u;
      s1[reg] += u;
      s2[reg] = fmaf(u, u, s2[reg]);
    }
  }
#pragma unroll
  for (int m = 1; m < 16; m <<= 1)
#pragma unroll
    for (int reg = 0; reg < 4; ++reg) {
      s1[reg] += __shfl_xor(s1[reg], m);
      s2[reg] += __shfl_xor(s2[reg], m);
    }
  if (ml == 0) {
#pragma unroll
    for (int reg = 0; reg < 4; ++reg) {
      ln1[wv * 16 + gq * 4 + reg] = s1[reg];
      ln2[wv * 16 + gq * 4 + reg] = s2[reg];
    }
  }
  __syncthreads();
  float mean[4], rsv[4];
#pragma unroll
  for (int reg = 0; reg < 4; ++reg) {
    float t1 = s1[reg] + ln1[(wv ^ 4) * 16 + gq * 4 + reg];
    float t2 = s2[reg] + ln2[(wv ^ 4) * 16 + gq * 4 + reg];
    float mn = t1 * 0.00390625f;
    float var = t2 * 0.00390625f - mn * mn;
    mean[reg] = mn;
    rsv[reg] = rsqrtf(var + 1e-5f);
  }
#pragma unroll
  for (int pt = 0; pt < 8; ++pt) {
    int p = ph * 128 + pt * 16 + ml;
    float gg = lng[p], bb = lnb[p];
#pragma unroll
    for (int reg = 0; reg < 4; ++reg) {
      float val = (acc[pt][reg] - mean[reg]) * rsv[reg] * gg + bb;
      up[(nt * 16 + gq * 4 + reg) * 264 + p] = f2bf(val);
    }
  }
  __syncthreads();

  f32x4 o0 = (f32x4){0.f, 0.f, 0.f, 0.f};
  f32x4 o1 = (f32x4){0.f, 0.f, 0.f, 0.f};
  const char* urow = (const char*)up + (size_t)(nt * 16 + ml) * 528;
  int ftA = ph * 2, ftB = ph * 2 + 1;
#pragma unroll
  for (int ks = 0; ks < 8; ++ks) {
    bf16x8 a = *(const bf16x8*)(urow + ks * 64 + gq * 16);
    bf16x8 bA = *(const bf16x8*)(w2f + ((ftA * 8 + ks) << 9) + (lane << 3));
    bf16x8 bB = *(const bf16x8*)(w2f + ((ftB * 8 + ks) << 9) + (lane << 3));
    o0 = __builtin_amdgcn_mfma_f32_16x16x32_bf16(a, bA, o0, 0, 0, 0);
    o1 = __builtin_amdgcn_mfma_f32_16x16x32_bf16(a, bB, o1, 0, 0, 0);
  }
  float b2A = b2[ftA * 16 + ml], b2B = b2[ftB * 16 + ml];
#pragma unroll
  for (int reg = 0; reg < 4; ++reg) {
    int nj = base + nt * 16 + gq * 4 + reg;
    if (nj < nN) {
      out[(size_t)nj * 64 + ftA * 16 + ml] = o0[reg] + b2A;
      out[(size_t)nj * 64 + ftB * 16 + ml] = o1[reg] + b2B;
    }
  }
}

extern "C" void kernel_launch(void* const* d_in, const int* in_sizes, int n_in,
                              void* d_out, int out_size, void* d_ws, size_t ws_size,
                              hipStream_t stream) {
  const float* x = (const float*)d_in[0];
  const void* edges = d_in[1];
  const float* conv_wl = (const float*)d_in[2];
  const float* conv_bl = (const float*)d_in[3];
  const float* conv_wr = (const float*)d_in[4];
  const float* ln_g = (const float*)d_in[5];
  const float* ln_b = (const float*)d_in[6];
  const float* adapter_w = (const float*)d_in[7];
  const float* adapter_b = (const float*)d_in[8];
  const float* mlp_w1 = (const float*)d_in[9];
  const float* mlp_b1 = (const float*)d_in[10];
  const float* mlp_lng = (const float*)d_in[11];
  const float* mlp_lnb = (const float*)d_in[12];
  const float* mlp_w2 = (const float*)d_in[13];
  const float* mlp_b2 = (const float*)d_in[14];

  const int N = in_sizes[0] / 64;
  const int E = in_sizes[1] / 2;
  const int NL = in_sizes[2] / (64 * 128);  // 5

  const int Na = (N + 63) & ~63;
  const int Ea = (E + 63) & ~63;
  const int nbk = (N + 255) / 256;  // buckets of 256 nodes (<=512)

  int* row_start = (int*)d_ws;
  int* csr_src = row_start + (Na + 64);
  int* bcnt = csr_src + (Ea + 256);
  int* bstart = bcnt + (nbk + 8);
  int* bcursor = bstart + (nbk + 8);
  unsigned short* wcatf = (unsigned short*)(bcursor + (nbk + 8));
  unsigned short* awbf = wcatf + (size_t)NL * 12288;
  unsigned short* w1f = awbf + 4096;
  unsigned short* w2f = w1f + 16384;
  unsigned short* b0 = w2f + 16384;
  unsigned short* b1m = b0 + (size_t)Na * 64;
  unsigned* bbuf = (unsigned*)b1m;  // alias: bbuf dead before layer 0 writes b1m
  float* outf = (float*)d_out;

  hipMemsetAsync(bcnt, 0, (size_t)(nbk + 8) * 4, stream);

  bucket_count<<<512, 256, 0, stream>>>(edges, bcnt, E, nbk);
  bucket_scan<<<1, 512, 0, stream>>>(bcnt, bstart, bcursor, row_start, nbk, E, N);
  const int chunk = 256 * SCH;
  const int nsb2 = (E + chunk - 1) / chunk;
  bucket_scatter<<<nsb2, 256, 0, stream>>>(edges, bcursor, bbuf, E, nbk);
  bucket_to_csr<<<nbk, 256, 0, stream>>>(bbuf, bstart, row_start, csr_src, N);

  int prep_tot = NL * 12288 + 4096 + 16384 + 16384;
  int n4 = N * 16;
  int prep_blocks = (prep_tot + n4 + 255) / 256;
  prep_all<<<prep_blocks, 256, 0, stream>>>(conv_wl, conv_wr, adapter_w, mlp_w1, mlp_w2,
                                            x, wcatf, awbf, w1f, w2f, b0, NL, n4);

  const int nb = (N + 63) / 64;
  for (int i = 0; i < NL; ++i) {
    const float* inf = (i == 0) ? x : outf;
    unsigned short* inb = (i & 1) ? b1m : b0;
    unsigned short* outb = (i & 1) ? b0 : b1m;
    const unsigned short* wc = wcatf + (size_t)i * 12288;
    const float* bl = conv_bl + (size_t)i * 64;
    const float* g = ln_g + (size_t)i * 64;
    const float* b = ln_b + (size_t)i * 64;
    int wf32 = (i == NL - 1) ? 0 : 1;
    if (i == 0) {
      sage_layer<true><<<nb, 256, 0, stream>>>(inf, inb, outf, outb, row_start, csr_src,
                                               wc, awbf, bl, adapter_b, g, b, N, wf32);
    } else {
      sage_layer<false><<<nb, 256, 0, stream>>>(inf, inb, outf, outb, row_start, csr_src,
                                                wc, awbf, bl, adapter_b, g, b, N, wf32);
    }
  }
  unsigned short* hb_final = ((NL - 1) & 1) ? b0 : b1m;
  mlp_head<<<nb, 512, 0, stream>>>(hb_final, outf, w1f, mlp_b1, mlp_lng, mlp_lnb,
                                   w2f, mlp_b2, N);
}